// Round 1
// baseline (21111.572 us; speedup 1.0000x reference)
//
#include <hip/hip_runtime.h>

// MyRNN: x_{t+1} = x_t + 0.1*(-x_t + (Jij*M) @ sigmoid(x_t) + II[:,t]), x_0 = 0
// out[2048][4096] row-major; col 0 = 0, cols 1..4095 = x_1..x_4095.
//
// Strategy: persistent kernel, J held in registers (64 fp32/lane), one custom
// grid barrier per step, state broadcast through a double-buffered global s_buf.

#define NN   2048
#define LT   4096
#define NBLK 128
#define TPB  512
#define ROWS_PER_BLK 16  // NN / NBLK

__device__ __forceinline__ void grid_barrier(unsigned* cnt, unsigned* gen, unsigned g)
{
    __syncthreads();
    if (threadIdx.x == 0) {
        // make this block's s_buf (and other) stores visible device-wide
        __builtin_amdgcn_fence(__ATOMIC_RELEASE, "agent");
        unsigned old = __hip_atomic_fetch_add(cnt, 1u, __ATOMIC_RELAXED, __HIP_MEMORY_SCOPE_AGENT);
        if (old == g * NBLK - 1u) {
            __hip_atomic_store(gen, g, __ATOMIC_RELAXED, __HIP_MEMORY_SCOPE_AGENT);
        } else {
            while (__hip_atomic_load(gen, __ATOMIC_RELAXED, __HIP_MEMORY_SCOPE_AGENT) < g) {
                // relaxed agent loads go to the coherence point (~L3 RT) -> naturally throttled
            }
        }
        // invalidate L1/L2 so subsequent plain loads see other XCDs' writes
        __builtin_amdgcn_fence(__ATOMIC_ACQUIRE, "agent");
    }
    __syncthreads();
}

__global__ __launch_bounds__(TPB, 1)
void rnn_persistent(const float* __restrict__ II,
                    const float* __restrict__ Jij,
                    const float* __restrict__ Mm,
                    float* __restrict__ out,
                    unsigned* cnt, unsigned* gen, float* sbuf)
{
    // s staged per step: 64 chunks of 32 floats, pad to 33 (bank = (chunk + j) % 32 -> 2-way, free)
    __shared__ float s_lds[64 * 33];

    const int tid  = threadIdx.x;
    const int lane = tid & 63;
    const int wv   = tid >> 6;                 // 0..7
    const int bid  = blockIdx.x;
    const int r0   = bid * ROWS_PER_BLK + 2 * wv;
    const int r1   = r0 + 1;
    const int colb = lane * 32;                // this lane's 32 columns

    // ---- one-time: load J_eff = Jij * M into registers (2 rows x 32 cols) ----
    float jr0[32], jr1[32];
    {
        const float4* a0 = reinterpret_cast<const float4*>(Jij + (size_t)r0 * NN + colb);
        const float4* m0 = reinterpret_cast<const float4*>(Mm  + (size_t)r0 * NN + colb);
        const float4* a1 = reinterpret_cast<const float4*>(Jij + (size_t)r1 * NN + colb);
        const float4* m1 = reinterpret_cast<const float4*>(Mm  + (size_t)r1 * NN + colb);
#pragma unroll
        for (int k = 0; k < 8; ++k) {
            float4 a = a0[k], m = m0[k];
            jr0[4*k+0] = a.x * m.x; jr0[4*k+1] = a.y * m.y;
            jr0[4*k+2] = a.z * m.z; jr0[4*k+3] = a.w * m.w;
            float4 b = a1[k], n = m1[k];
            jr1[4*k+0] = b.x * n.x; jr1[4*k+1] = b.y * n.y;
            jr1[4*k+2] = b.z * n.z; jr1[4*k+3] = b.w * n.w;
        }
    }

    // ---- init: x_0 = 0, s_0 = sigmoid(0) = 0.5, out col 0 = 0 ----
    float x0 = 0.f, x1 = 0.f;
    if (lane == 0) {
        out[(size_t)r0 * LT] = 0.f;
        out[(size_t)r1 * LT] = 0.f;
        __hip_atomic_store(sbuf + r0, 0.5f, __ATOMIC_RELAXED, __HIP_MEMORY_SCOPE_AGENT);
        __hip_atomic_store(sbuf + r1, 0.5f, __ATOMIC_RELAXED, __HIP_MEMORY_SCOPE_AGENT);
    }
    grid_barrier(cnt, gen, 1u);

    // ---- main loop: 4095 steps ----
    for (int t = 0; t < LT - 1; ++t) {
        // issue independent II loads early (latency hidden under staging/compute)
        float It0 = 0.f, It1 = 0.f;
        if (lane == 0) {
            It0 = II[(size_t)r0 * LT + t];
            It1 = II[(size_t)r1 * LT + t];
        }

        // stage s_t (parity t&1) into LDS: 2048 floats / 512 threads = 1 float4 each
        {
            const float* sb = sbuf + (size_t)(t & 1) * NN;
            float4 v = *reinterpret_cast<const float4*>(sb + tid * 4);
            int idx = tid * 4;
            float* p = s_lds + (idx >> 5) * 33 + (idx & 31);
            p[0] = v.x; p[1] = v.y; p[2] = v.z; p[3] = v.w;
        }
        __syncthreads();

        // dot products: 2 rows x 32 cols per lane
        float acc0 = 0.f, acc1 = 0.f;
        const float* sl = s_lds + lane * 33;
#pragma unroll
        for (int j = 0; j < 32; ++j) {
            float sv = sl[j];
            acc0 = fmaf(jr0[j], sv, acc0);
            acc1 = fmaf(jr1[j], sv, acc1);
        }
        // reduce across the 64-lane wave
#pragma unroll
        for (int off = 32; off > 0; off >>= 1) {
            acc0 += __shfl_down(acc0, off, 64);
            acc1 += __shfl_down(acc1, off, 64);
        }

        if (lane == 0) {
            x0 = x0 + 0.1f * (-x0 + acc0 + It0);
            x1 = x1 + 0.1f * (-x1 + acc1 + It1);
            out[(size_t)r0 * LT + t + 1] = x0;
            out[(size_t)r1 * LT + t + 1] = x1;
            float s0 = 1.f / (1.f + __expf(-x0));
            float s1 = 1.f / (1.f + __expf(-x1));
            float* sw = sbuf + (size_t)((t + 1) & 1) * NN;
            __hip_atomic_store(sw + r0, s0, __ATOMIC_RELAXED, __HIP_MEMORY_SCOPE_AGENT);
            __hip_atomic_store(sw + r1, s1, __ATOMIC_RELAXED, __HIP_MEMORY_SCOPE_AGENT);
        }

        grid_barrier(cnt, gen, (unsigned)(t + 2));
    }
}

extern "C" void kernel_launch(void* const* d_in, const int* in_sizes, int n_in,
                              void* d_out, int out_size, void* d_ws, size_t ws_size,
                              hipStream_t stream)
{
    const float* II  = (const float*)d_in[0];
    const float* Jij = (const float*)d_in[1];
    const float* Mm  = (const float*)d_in[2];
    float* out = (float*)d_out;

    unsigned char* ws = (unsigned char*)d_ws;
    unsigned* cnt = (unsigned*)(ws + 0);     // arrival counter (monotonic)
    unsigned* gen = (unsigned*)(ws + 128);   // generation flag (separate line)
    float*    sbuf = (float*)(ws + 256);     // double-buffered s [2][2048]

    // ws is re-poisoned to 0xAA before every timed replay -> re-zero control words
    hipMemsetAsync(d_ws, 0, 256, stream);

    rnn_persistent<<<NBLK, TPB, 0, stream>>>(II, Jij, Mm, out, cnt, gen, sbuf);
}